// Round 2
// baseline (387.664 us; speedup 1.0000x reference)
//
#include <hip/hip_runtime.h>

typedef unsigned short u16;
typedef __attribute__((ext_vector_type(8))) short bf16x8;
typedef __attribute__((ext_vector_type(4))) float f32x4;

// ---------- helpers ----------
__device__ __forceinline__ u16 f2b(float f) {
  unsigned u = __float_as_uint(f);
  u += 0x7FFFu + ((u >> 16) & 1u);   // RNE to bf16
  return (u16)(u >> 16);
}
__device__ __forceinline__ float sigm(float x) { return 1.0f / (1.0f + __expf(-x)); }
__device__ __forceinline__ float tanh_f(float x) { return 1.0f - 2.0f / (__expf(2.0f * x) + 1.0f); }

__device__ __forceinline__ void cp16(const u16* g, u16* l) {
  __builtin_amdgcn_global_load_lds(
      (const __attribute__((address_space(1))) unsigned int*)g,
      (__attribute__((address_space(3))) unsigned int*)l, 16, 0, 0);
}

// ---------- pack kernels (unchanged from R1) ----------
__global__ __launch_bounds__(256) void pack_xh(const float* __restrict__ x,
                                               const float* __restrict__ h,
                                               u16* __restrict__ xhb) {
  int idx = blockIdx.x * 256 + threadIdx.x;
  int row = idx >> 9;
  int k = (idx & 511) << 2;
  const float* src = (k < 1024) ? (x + row * 1024 + k) : (h + row * 1024 + (k - 1024));
  float4 v = *reinterpret_cast<const float4*>(src);
  ushort4 o = make_ushort4(f2b(v.x), f2b(v.y), f2b(v.z), f2b(v.w));
  *reinterpret_cast<ushort4*>(xhb + ((size_t)idx << 2)) = o;
}

__global__ __launch_bounds__(256) void pack_w1(const float* __restrict__ Wwz,
                                               const float* __restrict__ Wuz,
                                               const float* __restrict__ Wwr,
                                               const float* __restrict__ Wur,
                                               const float* __restrict__ Ww,
                                               u16* __restrict__ W1b) {
  int idx = blockIdx.x * 256 + threadIdx.x;
  int n = idx >> 9;
  int k = (idx & 511) << 2;
  float4 v = make_float4(0.f, 0.f, 0.f, 0.f);
  if (n < 1024) {
    v = (k < 1024) ? *reinterpret_cast<const float4*>(Wwz + n * 1024 + k)
                   : *reinterpret_cast<const float4*>(Wuz + n * 1024 + (k - 1024));
  } else if (n < 2048) {
    int nn = n - 1024;
    v = (k < 1024) ? *reinterpret_cast<const float4*>(Wwr + nn * 1024 + k)
                   : *reinterpret_cast<const float4*>(Wur + nn * 1024 + (k - 1024));
  } else {
    int nn = n - 2048;
    if (k < 1024) v = *reinterpret_cast<const float4*>(Ww + nn * 1024 + k);
  }
  ushort4 o = make_ushort4(f2b(v.x), f2b(v.y), f2b(v.z), f2b(v.w));
  *reinterpret_cast<ushort4*>(W1b + ((size_t)idx << 2)) = o;
}

__global__ __launch_bounds__(256) void pack_wu(const float* __restrict__ Wu,
                                               u16* __restrict__ Wub) {
  int idx = blockIdx.x * 256 + threadIdx.x;
  float4 v = *reinterpret_cast<const float4*>(Wu + ((size_t)idx << 2));
  ushort4 o = make_ushort4(f2b(v.x), f2b(v.y), f2b(v.z), f2b(v.w));
  *reinterpret_cast<ushort4*>(Wub + ((size_t)idx << 2)) = o;
}

// ---------- 8-phase 256x256 GEMM core (m201 template, plain HIP) ----------
// C[256x256] = A[256xK] * B[256xK]^T, A/B row-major bf16, pre-offset to tile origin.
// LDS layout per matrix per buffer: 2 halves x [128][64] bf16, swizzled
// physical_byte = logical_byte ^ ((logical_byte>>9 & 1) << 5) within each 16KB half.
// gload_lds writes linearly; the inverse swizzle is applied to the GLOBAL source.
__device__ __forceinline__ void core8(const u16* __restrict__ Ag, const u16* __restrict__ Bg,
                                      int lda, int ldb, int NT,
                                      u16* a_lds, u16* b_lds, f32x4 acc[8][4]) {
  const int tid = threadIdx.x;
  const int lane = tid & 63;
  const int wid = tid >> 6;
  const int wr = wid >> 2;   // 0..1  (M)
  const int wc = wid & 3;    // 0..3  (N)

  // staging decode: physical p = tid*16 within an 8KB round; logical = p ^ swz
  const int plo = tid * 16;
  const int olo = plo ^ (((plo >> 9) & 1) << 5);
  const int r0 = olo >> 7;        // row within 64-row round
  const int c2 = olo & 127;       // byte col within 128B row

  // fragment-read per-lane offset (u16 units), swizzle folded in:
  // bit5 flip = (row>>2)&1 = (lane>>2)&1 for all frags (row bases are mult of 4)
  const int arl = (((lane & 15) * 128) + (((lane >> 4) * 16) ^ (((lane >> 2) & 1) << 5))) >> 1;

  auto stageA = [&](int h, int tg, int tb) {
    const u16* g = Ag + (size_t)(h * 128 + r0) * lda + (c2 >> 1) + (size_t)tg * 64;
    u16* l = a_lds + tb * 16384 + h * 8192 + tid * 8;
    cp16(g, l);
    cp16(g + (size_t)64 * lda, l + 4096);
  };
  auto stageB = [&](int h, int tg, int tb) {
    const u16* g = Bg + (size_t)(h * 128 + r0) * ldb + (c2 >> 1) + (size_t)tg * 64;
    u16* l = b_lds + tb * 16384 + h * 8192 + tid * 8;
    cp16(g, l);
    cp16(g + (size_t)64 * ldb, l + 4096);
  };

  // prologue: tile0 A+B into buf0; tile1 B into buf1 (tile1 A staged at (0,q0/q1))
  stageA(0, 0, 0); stageA(1, 0, 0);
  stageB(0, 0, 0); stageB(1, 0, 0);
  stageB(0, 1, 1); stageB(1, 1, 1);
  asm volatile("s_waitcnt vmcnt(4)" ::: "memory");   // tile0 landed; tile1-B may fly
  __builtin_amdgcn_s_barrier();
  __builtin_amdgcn_sched_barrier(0);

  for (int t = 0; t < NT; ++t) {
    const int buf = t & 1;
    const int abase = buf * 16384 + wr * 8192;
    const int bbase = buf * 16384 + (wc >> 1) * 8192 + (wc & 1) * 4096;
    bf16x8 bfr[4][2];
#pragma unroll
    for (int q = 0; q < 4; ++q) {
      // 1. ds-reads for this phase (A quadrant; B all at q0)
      bf16x8 af[2][2];
#pragma unroll
      for (int m = 0; m < 2; ++m)
#pragma unroll
        for (int ks = 0; ks < 2; ++ks)
          af[m][ks] = *reinterpret_cast<const bf16x8*>(
              a_lds + abase + (q * 2 + m) * 1024 + ks * 32 + arl);
      if (q == 0) {
#pragma unroll
        for (int nf = 0; nf < 4; ++nf)
#pragma unroll
          for (int ks = 0; ks < 2; ++ks)
            bfr[nf][ks] = *reinterpret_cast<const bf16x8*>(
                b_lds + bbase + nf * 1024 + ks * 32 + arl);
      }
      // 2. stage one half-tile (consume-before-clobber schedule)
      if (q == 0)      { if (t + 1 < NT) stageA(0, t + 1, (t + 1) & 1); }
      else if (q == 1) { if (t + 1 < NT) stageA(1, t + 1, (t + 1) & 1); }
      else if (q == 2) { if (t + 2 < NT) stageB(0, t + 2, buf); }
      else             { if (t + 2 < NT) stageB(1, t + 2, buf);
                         asm volatile("s_waitcnt vmcnt(4)" ::: "memory"); }
      // 3. barrier -> MFMA cluster -> barrier
      __builtin_amdgcn_s_barrier();
      __builtin_amdgcn_sched_barrier(0);
      __builtin_amdgcn_s_setprio(1);
#pragma unroll
      for (int m = 0; m < 2; ++m)
#pragma unroll
        for (int nf = 0; nf < 4; ++nf)
#pragma unroll
          for (int ks = 0; ks < 2; ++ks)
            acc[q * 2 + m][nf] = __builtin_amdgcn_mfma_f32_16x16x32_bf16(
                af[m][ks], bfr[nf][ks], acc[q * 2 + m][nf], 0, 0, 0);
      __builtin_amdgcn_s_setprio(0);
      __builtin_amdgcn_s_barrier();
      __builtin_amdgcn_sched_barrier(0);
    }
  }
}

// GEMM1: [8192 x 3072] = xhb[8192x2048] @ W1b^T, fused GRU epilogue by column region
__global__ __launch_bounds__(512, 2) void gemm1_k(const u16* __restrict__ xhb,
                                                  const u16* __restrict__ W1b,
                                                  const float* __restrict__ h,
                                                  float* __restrict__ zout,
                                                  u16* __restrict__ rhb,
                                                  float* __restrict__ xwb) {
  __shared__ u16 a_lds[32768];
  __shared__ u16 b_lds[32768];
  const int m0 = blockIdx.y * 256;
  const int n0 = blockIdx.x * 256;
  const int NT = (n0 >= 2048) ? 16 : 32;   // W_w slice has K=1024
  f32x4 acc[8][4];
#pragma unroll
  for (int m = 0; m < 8; ++m)
#pragma unroll
    for (int n = 0; n < 4; ++n) acc[m][n] = (f32x4){0.f, 0.f, 0.f, 0.f};

  core8(xhb + (size_t)m0 * 2048, W1b + (size_t)n0 * 2048, 2048, 2048, NT, a_lds, b_lds, acc);

  const int lane = threadIdx.x & 63;
  const int wid = threadIdx.x >> 6;
  const int wr = wid >> 2, wc = wid & 3;
  const int rbase = m0 + wr * 128 + ((lane >> 4) << 2);
  const int cbase = n0 + wc * 64 + (lane & 15);
  const int region = n0 >> 10;   // 0=z, 1=r, 2=w (block-uniform)
#pragma unroll
  for (int mq = 0; mq < 8; ++mq) {
#pragma unroll
    for (int nf = 0; nf < 4; ++nf) {
      const int col = cbase + nf * 16;
#pragma unroll
      for (int j = 0; j < 4; ++j) {
        const int row = rbase + mq * 16 + j;
        const float v = acc[mq][nf][j];
        if (region == 0) {
          zout[(size_t)row * 1024 + col] = sigm(v);
        } else if (region == 1) {
          const size_t idx = (size_t)row * 1024 + (col - 1024);
          rhb[idx] = f2b(sigm(v) * h[idx]);
        } else {
          xwb[(size_t)row * 1024 + (col - 2048)] = v;
        }
      }
    }
  }
}

// GEMM2: C2 = rhb[8192x1024] @ Wub^T; out = z*h + (1-z)*tanh(C2 + xw)
__global__ __launch_bounds__(512, 2) void gemm2_k(const u16* __restrict__ rhb,
                                                  const u16* __restrict__ Wub,
                                                  const float* __restrict__ h,
                                                  const float* __restrict__ xwb,
                                                  float* __restrict__ out) {  // holds z on entry
  __shared__ u16 a_lds[32768];
  __shared__ u16 b_lds[32768];
  const int m0 = blockIdx.y * 256;
  const int n0 = blockIdx.x * 256;
  f32x4 acc[8][4];
#pragma unroll
  for (int m = 0; m < 8; ++m)
#pragma unroll
    for (int n = 0; n < 4; ++n) acc[m][n] = (f32x4){0.f, 0.f, 0.f, 0.f};

  core8(rhb + (size_t)m0 * 1024, Wub + (size_t)n0 * 1024, 1024, 1024, 16, a_lds, b_lds, acc);

  const int lane = threadIdx.x & 63;
  const int wid = threadIdx.x >> 6;
  const int wr = wid >> 2, wc = wid & 3;
  const int rbase = m0 + wr * 128 + ((lane >> 4) << 2);
  const int cbase = n0 + wc * 64 + (lane & 15);
#pragma unroll
  for (int mq = 0; mq < 8; ++mq) {
#pragma unroll
    for (int nf = 0; nf < 4; ++nf) {
      const int col = cbase + nf * 16;
#pragma unroll
      for (int j = 0; j < 4; ++j) {
        const int row = rbase + mq * 16 + j;
        const size_t idx = (size_t)row * 1024 + col;
        const float z = out[idx];
        const float hv = h[idx];
        const float ht = tanh_f(acc[mq][nf][j] + xwb[idx]);
        out[idx] = z * hv + (1.0f - z) * ht;
      }
    }
  }
}

// ---------- launch ----------
extern "C" void kernel_launch(void* const* d_in, const int* in_sizes, int n_in,
                              void* d_out, int out_size, void* d_ws, size_t ws_size,
                              hipStream_t stream) {
  const float* x   = (const float*)d_in[0];
  const float* h   = (const float*)d_in[1];
  const float* Wwz = (const float*)d_in[2];
  const float* Wuz = (const float*)d_in[3];
  const float* Wwr = (const float*)d_in[4];
  const float* Wur = (const float*)d_in[5];
  const float* Wu  = (const float*)d_in[6];
  const float* Ww  = (const float*)d_in[7];
  float* out = (float*)d_out;

  char* ws = (char*)d_ws;
  u16*   xhb = (u16*)(ws);                      // 8192*2048*2 = 33,554,432
  u16*   W1b = (u16*)(ws + 33554432);           // 3072*2048*2 = 12,582,912
  u16*   Wub = (u16*)(ws + 46137344);           // 1024*1024*2 =  2,097,152
  u16*   rhb = (u16*)(ws + 48234496);           // 8192*1024*2 = 16,777,216
  float* xwb = (float*)(ws + 65011712);         // 8192*1024*4 = 33,554,432

  pack_xh<<<16384, 256, 0, stream>>>(x, h, xhb);
  pack_w1<<<6144, 256, 0, stream>>>(Wwz, Wuz, Wwr, Wur, Ww, W1b);
  pack_wu<<<1024, 256, 0, stream>>>(Wu, Wub);
  gemm1_k<<<dim3(12, 32), 512, 0, stream>>>(xhb, W1b, h, out, rhb, xwb);
  gemm2_k<<<dim3(4, 32), 512, 0, stream>>>(rhb, Wub, h, xwb, out);
}

// Round 3
// 364.342 us; speedup vs baseline: 1.0640x; 1.0640x over previous
//
#include <hip/hip_runtime.h>

typedef unsigned short u16;
typedef __attribute__((ext_vector_type(8))) short bf16x8;
typedef __attribute__((ext_vector_type(4))) float f32x4;

// ---------- helpers ----------
__device__ __forceinline__ u16 f2b(float f) {
  unsigned u = __float_as_uint(f);
  u += 0x7FFFu + ((u >> 16) & 1u);   // RNE to bf16
  return (u16)(u >> 16);
}
__device__ __forceinline__ float sigm(float x) { return 1.0f / (1.0f + __expf(-x)); }
__device__ __forceinline__ float tanh_f(float x) { return 1.0f - 2.0f / (__expf(2.0f * x) + 1.0f); }

__device__ __forceinline__ void cp16(const u16* g, u16* l) {
  __builtin_amdgcn_global_load_lds(
      (const __attribute__((address_space(1))) unsigned int*)g,
      (__attribute__((address_space(3))) unsigned int*)l, 16, 0, 0);
}

// swizzle: byte ^= ((byte>>7)&3)<<5 ^ ((byte>>9)&1)<<4  (involution: bits 7-9 untouched)
__device__ __forceinline__ int swz(int b) {
  return b ^ (((b >> 7) & 3) << 5) ^ (((b >> 9) & 1) << 4);
}

// ---------- pack kernels ----------
__global__ __launch_bounds__(256) void pack_xh(const float* __restrict__ x,
                                               const float* __restrict__ h,
                                               u16* __restrict__ xhb) {
  int idx = blockIdx.x * 256 + threadIdx.x;
  int row = idx >> 9;
  int k = (idx & 511) << 2;
  const float* src = (k < 1024) ? (x + row * 1024 + k) : (h + row * 1024 + (k - 1024));
  float4 v = *reinterpret_cast<const float4*>(src);
  ushort4 o = make_ushort4(f2b(v.x), f2b(v.y), f2b(v.z), f2b(v.w));
  *reinterpret_cast<ushort4*>(xhb + ((size_t)idx << 2)) = o;
}

__global__ __launch_bounds__(256) void pack_w1(const float* __restrict__ Wwz,
                                               const float* __restrict__ Wuz,
                                               const float* __restrict__ Wwr,
                                               const float* __restrict__ Wur,
                                               const float* __restrict__ Ww,
                                               u16* __restrict__ W1b) {
  int idx = blockIdx.x * 256 + threadIdx.x;
  int n = idx >> 9;
  int k = (idx & 511) << 2;
  float4 v = make_float4(0.f, 0.f, 0.f, 0.f);
  if (n < 1024) {
    v = (k < 1024) ? *reinterpret_cast<const float4*>(Wwz + n * 1024 + k)
                   : *reinterpret_cast<const float4*>(Wuz + n * 1024 + (k - 1024));
  } else if (n < 2048) {
    int nn = n - 1024;
    v = (k < 1024) ? *reinterpret_cast<const float4*>(Wwr + nn * 1024 + k)
                   : *reinterpret_cast<const float4*>(Wur + nn * 1024 + (k - 1024));
  } else {
    int nn = n - 2048;
    if (k < 1024) v = *reinterpret_cast<const float4*>(Ww + nn * 1024 + k);
  }
  ushort4 o = make_ushort4(f2b(v.x), f2b(v.y), f2b(v.z), f2b(v.w));
  *reinterpret_cast<ushort4*>(W1b + ((size_t)idx << 2)) = o;
}

__global__ __launch_bounds__(256) void pack_wu(const float* __restrict__ Wu,
                                               u16* __restrict__ Wub) {
  int idx = blockIdx.x * 256 + threadIdx.x;
  float4 v = *reinterpret_cast<const float4*>(Wu + ((size_t)idx << 2));
  ushort4 o = make_ushort4(f2b(v.x), f2b(v.y), f2b(v.z), f2b(v.w));
  *reinterpret_cast<ushort4*>(Wub + ((size_t)idx << 2)) = o;
}

// ---------- 8-phase 256x256 GEMM core ----------
// C[256x256] = A[256xK] * B[256xK]^T. LDS: per matrix 2 buffers x 2 halves x [128][64] bf16,
// swizzled via swz(); gload_lds dest linear, inverse swizzle on global source, swizzled ds_read.
__device__ __forceinline__ void core8(const u16* __restrict__ Ag, const u16* __restrict__ Bg,
                                      int lda, int ldb, int NT,
                                      u16* a_lds, u16* b_lds, f32x4 acc[8][4]) {
  const int tid = threadIdx.x;
  const int lane = tid & 63;
  const int wid = tid >> 6;
  const int wr = wid >> 2;   // 0..1  (M)
  const int wc = wid & 3;    // 0..3  (N)

  // staging decode: physical byte p = tid*16 within 8KB round; logical l = swz(p)
  const int plo = tid * 16;
  const int olo = swz(plo);
  const int r0 = olo >> 7;        // row within 64-row round
  const int c2 = (olo & 127) >> 1;  // u16 col

  // fragment-read per-lane byte offsets (ks=0,1), swizzle folded in
  const int frow = lane & 15;
  const int fcb = (lane >> 4) * 16;
  const int arl0 = (frow * 128 + swz(fcb)) >> 1;          // swz only touches bits 4-6 of col
  const int mask = (((frow & 3) << 5) | (((frow >> 2) & 1) << 4));
  const int arl0x = (frow * 128 + ((fcb + 0) ^ mask)) >> 1;
  const int arl1x = (frow * 128 + ((fcb + 64) ^ mask)) >> 1;
  (void)arl0;

  auto stageA = [&](int hh, int tg, int tb) {
    const u16* g = Ag + (size_t)(hh * 128 + r0) * lda + c2 + (size_t)tg * 64;
    u16* l = a_lds + tb * 16384 + hh * 8192 + tid * 8;
    cp16(g, l);
    cp16(g + (size_t)64 * lda, l + 4096);
  };
  auto stageB = [&](int hh, int tg, int tb) {
    const u16* g = Bg + (size_t)(hh * 128 + r0) * ldb + c2 + (size_t)tg * 64;
    u16* l = b_lds + tb * 16384 + hh * 8192 + tid * 8;
    cp16(g, l);
    cp16(g + (size_t)64 * ldb, l + 4096);
  };

  // prologue: tile0 A+B -> buf0; tile1 B -> buf1 (tile1 A staged during tile0 q0/q1)
  stageA(0, 0, 0); stageA(1, 0, 0);
  stageB(0, 0, 0); stageB(1, 0, 0);
  stageB(0, 1, 1); stageB(1, 1, 1);
  asm volatile("s_waitcnt vmcnt(4)" ::: "memory");   // tile0 landed; tile1-B may fly
  __builtin_amdgcn_s_barrier();

  for (int t = 0; t < NT; ++t) {
    const int buf = t & 1;
    const int abase = buf * 16384 + wr * 8192;
    const int bbase = buf * 16384 + (wc >> 1) * 8192 + (wc & 1) * 4096;
    bf16x8 bfr[4][2];
#pragma unroll
    for (int q = 0; q < 4; ++q) {
      // 1. ds-reads for this phase (A quadrant; all B at q0)
      bf16x8 af[2][2];
#pragma unroll
      for (int m = 0; m < 2; ++m) {
        af[m][0] = *reinterpret_cast<const bf16x8*>(a_lds + abase + (q * 2 + m) * 1024 + arl0x);
        af[m][1] = *reinterpret_cast<const bf16x8*>(a_lds + abase + (q * 2 + m) * 1024 + arl1x);
      }
      if (q == 0) {
#pragma unroll
        for (int nf = 0; nf < 4; ++nf) {
          bfr[nf][0] = *reinterpret_cast<const bf16x8*>(b_lds + bbase + nf * 1024 + arl0x);
          bfr[nf][1] = *reinterpret_cast<const bf16x8*>(b_lds + bbase + nf * 1024 + arl1x);
        }
      }
      // 2. stage one half-tile (consume-before-clobber)
      if (q == 0)      { if (t + 1 < NT) stageA(0, t + 1, (t + 1) & 1); }
      else if (q == 1) { if (t + 1 < NT) stageA(1, t + 1, (t + 1) & 1); }
      else if (q == 2) { if (t + 2 < NT) stageB(0, t + 2, buf); }
      else             { if (t + 2 < NT) stageB(1, t + 2, buf);
                         asm volatile("s_waitcnt vmcnt(4)" ::: "memory"); }
      // 3. barrier -> MFMA cluster -> barrier
      __builtin_amdgcn_s_barrier();
      __builtin_amdgcn_s_setprio(1);
#pragma unroll
      for (int m = 0; m < 2; ++m)
#pragma unroll
        for (int nf = 0; nf < 4; ++nf)
#pragma unroll
          for (int ks = 0; ks < 2; ++ks)
            acc[q * 2 + m][nf] = __builtin_amdgcn_mfma_f32_16x16x32_bf16(
                af[m][ks], bfr[nf][ks], acc[q * 2 + m][nf], 0, 0, 0);
      __builtin_amdgcn_s_setprio(0);
      __builtin_amdgcn_s_barrier();
    }
  }
}

// GEMM1: [8192 x 3072] = xhb[8192x2048] @ W1b^T, fused GRU epilogue by column region
__global__ __launch_bounds__(512, 2) void gemm1_k(const u16* __restrict__ xhb,
                                                  const u16* __restrict__ W1b,
                                                  const float* __restrict__ h,
                                                  float* __restrict__ zout,
                                                  u16* __restrict__ rhb,
                                                  float* __restrict__ xwb) {
  __shared__ u16 a_lds[32768];
  __shared__ u16 b_lds[32768];
  const int m0 = blockIdx.y * 256;
  const int n0 = blockIdx.x * 256;
  const int NT = (n0 >= 2048) ? 16 : 32;
  f32x4 acc[8][4];
#pragma unroll
  for (int m = 0; m < 8; ++m)
#pragma unroll
    for (int n = 0; n < 4; ++n) acc[m][n] = (f32x4){0.f, 0.f, 0.f, 0.f};

  core8(xhb + (size_t)m0 * 2048, W1b + (size_t)n0 * 2048, 2048, 2048, NT, a_lds, b_lds, acc);

  const int lane = threadIdx.x & 63;
  const int wid = threadIdx.x >> 6;
  const int wr = wid >> 2, wc = wid & 3;
  const int rbase = m0 + wr * 128 + ((lane >> 4) << 2);
  const int cbase = n0 + wc * 64 + (lane & 15);
  const int region = n0 >> 10;   // 0=z, 1=r, 2=w
#pragma unroll
  for (int mq = 0; mq < 8; ++mq) {
#pragma unroll
    for (int nf = 0; nf < 4; ++nf) {
      const int col = cbase + nf * 16;
#pragma unroll
      for (int j = 0; j < 4; ++j) {
        const int row = rbase + mq * 16 + j;
        const float v = acc[mq][nf][j];
        if (region == 0) {
          zout[(size_t)row * 1024 + col] = sigm(v);
        } else if (region == 1) {
          const size_t idx = (size_t)row * 1024 + (col - 1024);
          rhb[idx] = f2b(sigm(v) * h[idx]);
        } else {
          xwb[(size_t)row * 1024 + (col - 2048)] = v;
        }
      }
    }
  }
}

// ---------- 2-phase 128x128 core (R1-proven) for GEMM2 ----------
__device__ __forceinline__ void gemm_core128(const u16* __restrict__ A, const u16* __restrict__ Bm,
                                             int lda, int ldb, int m0, int n0, int ksteps,
                                             u16* a_lds, u16* b_lds, f32x4 acc[4][4]) {
  const int tid = threadIdx.x;
  const int lane = tid & 63;
  const int wave = tid >> 6;
  const int wr = wave >> 1, wc = wave & 1;
  const int srow = tid >> 2;
  const int scol = (tid & 3) << 3;
  const u16* ga = A + (size_t)(m0 + srow) * lda + scol;
  const u16* gb = Bm + (size_t)(n0 + srow) * ldb + scol;
  u16* la = a_lds + tid * 8;
  u16* lb = b_lds + tid * 8;
  const int fr = lane & 15;
  const int fk = (lane >> 4) << 3;

  for (int kt = 0; kt < ksteps; ++kt) {
    const int k0 = kt * 32;
    cp16(ga + k0, la);
    cp16(ga + (size_t)64 * lda + k0, la + 64 * 32);
    cp16(gb + k0, lb);
    cp16(gb + (size_t)64 * ldb + k0, lb + 64 * 32);
    __syncthreads();

    bf16x8 af[4], bfr[4];
#pragma unroll
    for (int m = 0; m < 4; ++m)
      af[m] = *reinterpret_cast<const bf16x8*>(&a_lds[(wr * 64 + m * 16 + fr) * 32 + fk]);
#pragma unroll
    for (int n = 0; n < 4; ++n)
      bfr[n] = *reinterpret_cast<const bf16x8*>(&b_lds[(wc * 64 + n * 16 + fr) * 32 + fk]);
#pragma unroll
    for (int m = 0; m < 4; ++m)
#pragma unroll
      for (int n = 0; n < 4; ++n)
        acc[m][n] = __builtin_amdgcn_mfma_f32_16x16x32_bf16(af[m], bfr[n], acc[m][n], 0, 0, 0);
    __syncthreads();
  }
}

// GEMM2: C2 = rhb[8192x1024] @ Wub^T; out = z*h + (1-z)*tanh(C2 + xw)
__global__ __launch_bounds__(256) void gemm2_k(const u16* __restrict__ rhb,
                                               const u16* __restrict__ Wub,
                                               const float* __restrict__ h,
                                               const float* __restrict__ xwb,
                                               float* __restrict__ out) {  // holds z on entry
  __shared__ u16 a_lds[128 * 32];
  __shared__ u16 b_lds[128 * 32];
  const int m0 = blockIdx.y * 128;
  const int n0 = blockIdx.x * 128;
  f32x4 acc[4][4];
#pragma unroll
  for (int m = 0; m < 4; ++m)
#pragma unroll
    for (int n = 0; n < 4; ++n) acc[m][n] = (f32x4){0.f, 0.f, 0.f, 0.f};

  gemm_core128(rhb, Wub, 1024, 1024, m0, n0, 32, a_lds, b_lds, acc);

  const int lane = threadIdx.x & 63;
  const int wave = threadIdx.x >> 6;
  const int wr = wave >> 1, wc = wave & 1;
  const int rbase = m0 + wr * 64 + ((lane >> 4) << 2);
  const int cbase = n0 + wc * 64 + (lane & 15);
#pragma unroll
  for (int m = 0; m < 4; ++m) {
#pragma unroll
    for (int n = 0; n < 4; ++n) {
      const int col = cbase + n * 16;
#pragma unroll
      for (int j = 0; j < 4; ++j) {
        const int row = rbase + m * 16 + j;
        const size_t idx = (size_t)row * 1024 + col;
        const float z = out[idx];
        const float hv = h[idx];
        const float ht = tanh_f(acc[m][n][j] + xwb[idx]);
        out[idx] = z * hv + (1.0f - z) * ht;
      }
    }
  }
}

// ---------- launch ----------
extern "C" void kernel_launch(void* const* d_in, const int* in_sizes, int n_in,
                              void* d_out, int out_size, void* d_ws, size_t ws_size,
                              hipStream_t stream) {
  const float* x   = (const float*)d_in[0];
  const float* h   = (const float*)d_in[1];
  const float* Wwz = (const float*)d_in[2];
  const float* Wuz = (const float*)d_in[3];
  const float* Wwr = (const float*)d_in[4];
  const float* Wur = (const float*)d_in[5];
  const float* Wu  = (const float*)d_in[6];
  const float* Ww  = (const float*)d_in[7];
  float* out = (float*)d_out;

  char* ws = (char*)d_ws;
  u16*   xhb = (u16*)(ws);                      // 33,554,432
  u16*   W1b = (u16*)(ws + 33554432);           // 12,582,912
  u16*   Wub = (u16*)(ws + 46137344);           //  2,097,152
  u16*   rhb = (u16*)(ws + 48234496);           // 16,777,216
  float* xwb = (float*)(ws + 65011712);         // 33,554,432

  pack_xh<<<16384, 256, 0, stream>>>(x, h, xhb);
  pack_w1<<<6144, 256, 0, stream>>>(Wwz, Wuz, Wwr, Wur, Ww, W1b);
  pack_wu<<<1024, 256, 0, stream>>>(Wu, Wub);
  gemm1_k<<<dim3(12, 32), 512, 0, stream>>>(xhb, W1b, h, out, rhb, xwb);
  gemm2_k<<<dim3(8, 64), 256, 0, stream>>>(rhb, Wub, h, xwb, out);
}

// Round 4
// 342.112 us; speedup vs baseline: 1.1332x; 1.0650x over previous
//
#include <hip/hip_runtime.h>

typedef unsigned short u16;
typedef __attribute__((ext_vector_type(8))) short bf16x8;
typedef __attribute__((ext_vector_type(4))) float f32x4;

// ---------- helpers ----------
__device__ __forceinline__ u16 f2b(float f) {
  unsigned u = __float_as_uint(f);
  u += 0x7FFFu + ((u >> 16) & 1u);   // RNE to bf16
  return (u16)(u >> 16);
}
__device__ __forceinline__ float sigm(float x) { return 1.0f / (1.0f + __expf(-x)); }
__device__ __forceinline__ float tanh_f(float x) { return 1.0f - 2.0f / (__expf(2.0f * x) + 1.0f); }

__device__ __forceinline__ void cp16(const u16* g, u16* l) {
  __builtin_amdgcn_global_load_lds(
      (const __attribute__((address_space(1))) unsigned int*)g,
      (__attribute__((address_space(3))) unsigned int*)l, 16, 0, 0);
}

// swizzle involution on bytes-within-8KB-round: flips col bits 4-6 by row mod 8
__device__ __forceinline__ int swz(int b) {
  return b ^ (((b >> 7) & 3) << 5) ^ (((b >> 9) & 1) << 4);
}

// ---------- pack kernels ----------
__global__ __launch_bounds__(256) void pack_xh(const float* __restrict__ x,
                                               const float* __restrict__ h,
                                               u16* __restrict__ xhb) {
  int idx = blockIdx.x * 256 + threadIdx.x;
  int row = idx >> 9;
  int k = (idx & 511) << 2;
  const float* src = (k < 1024) ? (x + row * 1024 + k) : (h + row * 1024 + (k - 1024));
  float4 v = *reinterpret_cast<const float4*>(src);
  ushort4 o = make_ushort4(f2b(v.x), f2b(v.y), f2b(v.z), f2b(v.w));
  *reinterpret_cast<ushort4*>(xhb + ((size_t)idx << 2)) = o;
}

__global__ __launch_bounds__(256) void pack_w1(const float* __restrict__ Wwz,
                                               const float* __restrict__ Wuz,
                                               const float* __restrict__ Wwr,
                                               const float* __restrict__ Wur,
                                               const float* __restrict__ Ww,
                                               u16* __restrict__ W1b) {
  int idx = blockIdx.x * 256 + threadIdx.x;
  int n = idx >> 9;
  int k = (idx & 511) << 2;
  float4 v = make_float4(0.f, 0.f, 0.f, 0.f);
  if (n < 1024) {
    v = (k < 1024) ? *reinterpret_cast<const float4*>(Wwz + n * 1024 + k)
                   : *reinterpret_cast<const float4*>(Wuz + n * 1024 + (k - 1024));
  } else if (n < 2048) {
    int nn = n - 1024;
    v = (k < 1024) ? *reinterpret_cast<const float4*>(Wwr + nn * 1024 + k)
                   : *reinterpret_cast<const float4*>(Wur + nn * 1024 + (k - 1024));
  } else {
    int nn = n - 2048;
    if (k < 1024) v = *reinterpret_cast<const float4*>(Ww + nn * 1024 + k);
  }
  ushort4 o = make_ushort4(f2b(v.x), f2b(v.y), f2b(v.z), f2b(v.w));
  *reinterpret_cast<ushort4*>(W1b + ((size_t)idx << 2)) = o;
}

__global__ __launch_bounds__(256) void pack_wu(const float* __restrict__ Wu,
                                               u16* __restrict__ Wub) {
  int idx = blockIdx.x * 256 + threadIdx.x;
  float4 v = *reinterpret_cast<const float4*>(Wu + ((size_t)idx << 2));
  ushort4 o = make_ushort4(f2b(v.x), f2b(v.y), f2b(v.z), f2b(v.w));
  *reinterpret_cast<ushort4*>(Wub + ((size_t)idx << 2)) = o;
}

// ---------- 8-phase 256x256 core, compile-time buffer parity ----------
// One K-tile (BK=64). Reads Ar/Br; stages A(u+1)->Aw, B(u+2)->Bw (Bw==Br object).
__device__ __forceinline__ void tile_body(int u, int NT,
                                          const u16* __restrict__ Ag, const u16* __restrict__ Bg,
                                          int lda, int ldb,
                                          const u16* Ar, const u16* Br, u16* Aw, u16* Bw,
                                          int r0, int c2, int arl0x, int arl1x,
                                          int wr, int wc, int tid, f32x4 acc[8][4]) {
  const int abase = wr * 8192;
  const int bbase = (wc >> 1) * 8192 + (wc & 1) * 4096;
  bf16x8 bfr[4][2];
#pragma unroll
  for (int q = 0; q < 4; ++q) {
    bf16x8 af[2][2];
#pragma unroll
    for (int m = 0; m < 2; ++m) {
      af[m][0] = *reinterpret_cast<const bf16x8*>(Ar + abase + (q * 2 + m) * 1024 + arl0x);
      af[m][1] = *reinterpret_cast<const bf16x8*>(Ar + abase + (q * 2 + m) * 1024 + arl1x);
    }
    if (q == 0) {
#pragma unroll
      for (int nf = 0; nf < 4; ++nf) {
        bfr[nf][0] = *reinterpret_cast<const bf16x8*>(Br + bbase + nf * 1024 + arl0x);
        bfr[nf][1] = *reinterpret_cast<const bf16x8*>(Br + bbase + nf * 1024 + arl1x);
      }
    }
    // stage one half-tile (consume-before-clobber; targets are distinct objects)
    if (q == 0) {
      if (u + 1 < NT) {
        const u16* g = Ag + (size_t)r0 * lda + c2 + (size_t)(u + 1) * 64;
        u16* l = Aw + tid * 8;
        cp16(g, l); cp16(g + (size_t)64 * lda, l + 4096);
      }
    } else if (q == 1) {
      if (u + 1 < NT) {
        const u16* g = Ag + (size_t)(128 + r0) * lda + c2 + (size_t)(u + 1) * 64;
        u16* l = Aw + 8192 + tid * 8;
        cp16(g, l); cp16(g + (size_t)64 * lda, l + 4096);
      }
    } else if (q == 2) {
      if (u + 2 < NT) {
        const u16* g = Bg + (size_t)r0 * ldb + c2 + (size_t)(u + 2) * 64;
        u16* l = Bw + tid * 8;
        cp16(g, l); cp16(g + (size_t)64 * ldb, l + 4096);
      }
    } else {
      if (u + 2 < NT) {
        const u16* g = Bg + (size_t)(128 + r0) * ldb + c2 + (size_t)(u + 2) * 64;
        u16* l = Bw + 8192 + tid * 8;
        cp16(g, l); cp16(g + (size_t)64 * ldb, l + 4096);
        asm volatile("s_waitcnt vmcnt(4)" ::: "memory");   // keep next tile's B in flight
      } else {
        asm volatile("s_waitcnt vmcnt(0)" ::: "memory");   // tail: drain everything
      }
    }
    __builtin_amdgcn_s_barrier();
    __builtin_amdgcn_s_setprio(1);
#pragma unroll
    for (int m = 0; m < 2; ++m)
#pragma unroll
      for (int nf = 0; nf < 4; ++nf)
#pragma unroll
        for (int ks = 0; ks < 2; ++ks)
          acc[q * 2 + m][nf] = __builtin_amdgcn_mfma_f32_16x16x32_bf16(
              af[m][ks], bfr[nf][ks], acc[q * 2 + m][nf], 0, 0, 0);
    __builtin_amdgcn_s_setprio(0);
    __builtin_amdgcn_s_barrier();
  }
}

__device__ __forceinline__ void core8(const u16* __restrict__ Ag, const u16* __restrict__ Bg,
                                      int lda, int ldb, int NT,
                                      u16* As0, u16* As1, u16* Bs0, u16* Bs1,
                                      f32x4 acc[8][4]) {
  const int tid = threadIdx.x;
  const int lane = tid & 63;
  const int wid = tid >> 6;
  const int wr = wid >> 2;
  const int wc = wid & 3;

  // staging decode: physical byte p = tid*16 in 8KB round; logical = swz(p)
  const int plo = tid * 16;
  const int olo = swz(plo);
  const int r0 = olo >> 7;
  const int c2 = (olo & 127) >> 1;

  // swizzled fragment-read offsets (u16 units)
  const int frow = lane & 15;
  const int fcb = (lane >> 4) * 16;
  const int mask = ((frow & 3) << 5) | (((frow >> 2) & 1) << 4);
  const int arl0x = (frow * 128 + ((fcb + 0) ^ mask)) >> 1;
  const int arl1x = (frow * 128 + ((fcb + 64) ^ mask)) >> 1;

  // prologue: tile0 A,B -> As0,Bs0; tile1 B -> Bs1
  {
    const u16* g; u16* l;
    g = Ag + (size_t)r0 * lda + c2;               l = As0 + tid * 8;        cp16(g, l); cp16(g + (size_t)64 * lda, l + 4096);
    g = Ag + (size_t)(128 + r0) * lda + c2;       l = As0 + 8192 + tid * 8; cp16(g, l); cp16(g + (size_t)64 * lda, l + 4096);
    g = Bg + (size_t)r0 * ldb + c2;               l = Bs0 + tid * 8;        cp16(g, l); cp16(g + (size_t)64 * ldb, l + 4096);
    g = Bg + (size_t)(128 + r0) * ldb + c2;       l = Bs0 + 8192 + tid * 8; cp16(g, l); cp16(g + (size_t)64 * ldb, l + 4096);
    g = Bg + (size_t)r0 * ldb + c2 + 64;          l = Bs1 + tid * 8;        cp16(g, l); cp16(g + (size_t)64 * ldb, l + 4096);
    g = Bg + (size_t)(128 + r0) * ldb + c2 + 64;  l = Bs1 + 8192 + tid * 8; cp16(g, l); cp16(g + (size_t)64 * ldb, l + 4096);
  }
  asm volatile("s_waitcnt vmcnt(4)" ::: "memory");   // tile0 landed; tile1-B in flight
  __builtin_amdgcn_s_barrier();

  for (int u = 0; u < NT; u += 2) {
    tile_body(u,     NT, Ag, Bg, lda, ldb, As0, Bs0, As1, Bs0, r0, c2, arl0x, arl1x, wr, wc, tid, acc);
    tile_body(u + 1, NT, Ag, Bg, lda, ldb, As1, Bs1, As0, Bs1, r0, c2, arl0x, arl1x, wr, wc, tid, acc);
  }
}

// GEMM1: [8192 x 3072] = xhb[8192x2048] @ W1b^T, fused GRU epilogue by column region
__global__ __launch_bounds__(512, 2) void gemm1_k(const u16* __restrict__ xhb,
                                                  const u16* __restrict__ W1b,
                                                  const float* __restrict__ h,
                                                  float* __restrict__ zout,
                                                  u16* __restrict__ rhb,
                                                  float* __restrict__ xwb) {
  __shared__ u16 As0[16384];
  __shared__ u16 As1[16384];
  __shared__ u16 Bs0[16384];
  __shared__ u16 Bs1[16384];
  const int m0 = blockIdx.y * 256;
  const int n0 = blockIdx.x * 256;
  const int NT = (n0 >= 2048) ? 16 : 32;
  f32x4 acc[8][4];
#pragma unroll
  for (int m = 0; m < 8; ++m)
#pragma unroll
    for (int n = 0; n < 4; ++n) acc[m][n] = (f32x4){0.f, 0.f, 0.f, 0.f};

  core8(xhb + (size_t)m0 * 2048, W1b + (size_t)n0 * 2048, 2048, 2048, NT,
        As0, As1, Bs0, Bs1, acc);

  const int lane = threadIdx.x & 63;
  const int wid = threadIdx.x >> 6;
  const int wr = wid >> 2, wc = wid & 3;
  const int rbase = m0 + wr * 128 + ((lane >> 4) << 2);
  const int cbase = n0 + wc * 64 + (lane & 15);
  const int region = n0 >> 10;   // 0=z, 1=r, 2=w
#pragma unroll
  for (int mq = 0; mq < 8; ++mq) {
#pragma unroll
    for (int nf = 0; nf < 4; ++nf) {
      const int col = cbase + nf * 16;
#pragma unroll
      for (int j = 0; j < 4; ++j) {
        const int row = rbase + mq * 16 + j;
        const float v = acc[mq][nf][j];
        if (region == 0) {
          zout[(size_t)row * 1024 + col] = sigm(v);
        } else if (region == 1) {
          const size_t idx = (size_t)row * 1024 + (col - 1024);
          rhb[idx] = f2b(sigm(v) * h[idx]);
        } else {
          xwb[(size_t)row * 1024 + (col - 2048)] = v;
        }
      }
    }
  }
}

// ---------- 2-phase 128x128 core (R1-proven) for GEMM2 ----------
__device__ __forceinline__ void gemm_core128(const u16* __restrict__ A, const u16* __restrict__ Bm,
                                             int lda, int ldb, int m0, int n0, int ksteps,
                                             u16* a_lds, u16* b_lds, f32x4 acc[4][4]) {
  const int tid = threadIdx.x;
  const int lane = tid & 63;
  const int wave = tid >> 6;
  const int wr = wave >> 1, wc = wave & 1;
  const int srow = tid >> 2;
  const int scol = (tid & 3) << 3;
  const u16* ga = A + (size_t)(m0 + srow) * lda + scol;
  const u16* gb = Bm + (size_t)(n0 + srow) * ldb + scol;
  u16* la = a_lds + tid * 8;
  u16* lb = b_lds + tid * 8;
  const int fr = lane & 15;
  const int fk = (lane >> 4) << 3;

  for (int kt = 0; kt < ksteps; ++kt) {
    const int k0 = kt * 32;
    cp16(ga + k0, la);
    cp16(ga + (size_t)64 * lda + k0, la + 64 * 32);
    cp16(gb + k0, lb);
    cp16(gb + (size_t)64 * ldb + k0, lb + 64 * 32);
    __syncthreads();

    bf16x8 af[4], bfr[4];
#pragma unroll
    for (int m = 0; m < 4; ++m)
      af[m] = *reinterpret_cast<const bf16x8*>(&a_lds[(wr * 64 + m * 16 + fr) * 32 + fk]);
#pragma unroll
    for (int n = 0; n < 4; ++n)
      bfr[n] = *reinterpret_cast<const bf16x8*>(&b_lds[(wc * 64 + n * 16 + fr) * 32 + fk]);
#pragma unroll
    for (int m = 0; m < 4; ++m)
#pragma unroll
      for (int n = 0; n < 4; ++n)
        acc[m][n] = __builtin_amdgcn_mfma_f32_16x16x32_bf16(af[m], bfr[n], acc[m][n], 0, 0, 0);
    __syncthreads();
  }
}

// GEMM2: C2 = rhb[8192x1024] @ Wub^T; out = z*h + (1-z)*tanh(C2 + xw)
__global__ __launch_bounds__(256) void gemm2_k(const u16* __restrict__ rhb,
                                               const u16* __restrict__ Wub,
                                               const float* __restrict__ h,
                                               const float* __restrict__ xwb,
                                               float* __restrict__ out) {  // holds z on entry
  __shared__ u16 a_lds[128 * 32];
  __shared__ u16 b_lds[128 * 32];
  const int m0 = blockIdx.y * 128;
  const int n0 = blockIdx.x * 128;
  f32x4 acc[4][4];
#pragma unroll
  for (int m = 0; m < 4; ++m)
#pragma unroll
    for (int n = 0; n < 4; ++n) acc[m][n] = (f32x4){0.f, 0.f, 0.f, 0.f};

  gemm_core128(rhb, Wub, 1024, 1024, m0, n0, 32, a_lds, b_lds, acc);

  const int lane = threadIdx.x & 63;
  const int wave = threadIdx.x >> 6;
  const int wr = wave >> 1, wc = wave & 1;
  const int rbase = m0 + wr * 64 + ((lane >> 4) << 2);
  const int cbase = n0 + wc * 64 + (lane & 15);
#pragma unroll
  for (int m = 0; m < 4; ++m) {
#pragma unroll
    for (int n = 0; n < 4; ++n) {
      const int col = cbase + n * 16;
#pragma unroll
      for (int j = 0; j < 4; ++j) {
        const int row = rbase + m * 16 + j;
        const size_t idx = (size_t)row * 1024 + col;
        const float z = out[idx];
        const float hv = h[idx];
        const float ht = tanh_f(acc[m][n][j] + xwb[idx]);
        out[idx] = z * hv + (1.0f - z) * ht;
      }
    }
  }
}

// ---------- launch ----------
extern "C" void kernel_launch(void* const* d_in, const int* in_sizes, int n_in,
                              void* d_out, int out_size, void* d_ws, size_t ws_size,
                              hipStream_t stream) {
  const float* x   = (const float*)d_in[0];
  const float* h   = (const float*)d_in[1];
  const float* Wwz = (const float*)d_in[2];
  const float* Wuz = (const float*)d_in[3];
  const float* Wwr = (const float*)d_in[4];
  const float* Wur = (const float*)d_in[5];
  const float* Wu  = (const float*)d_in[6];
  const float* Ww  = (const float*)d_in[7];
  float* out = (float*)d_out;

  char* ws = (char*)d_ws;
  u16*   xhb = (u16*)(ws);                      // 33,554,432
  u16*   W1b = (u16*)(ws + 33554432);           // 12,582,912
  u16*   Wub = (u16*)(ws + 46137344);           //  2,097,152
  u16*   rhb = (u16*)(ws + 48234496);           // 16,777,216
  float* xwb = (float*)(ws + 65011712);         // 33,554,432

  pack_xh<<<16384, 256, 0, stream>>>(x, h, xhb);
  pack_w1<<<6144, 256, 0, stream>>>(Wwz, Wuz, Wwr, Wur, Ww, W1b);
  pack_wu<<<1024, 256, 0, stream>>>(Wu, Wub);
  gemm1_k<<<dim3(12, 32), 512, 0, stream>>>(xhb, W1b, h, out, rhb, xwb);
  gemm2_k<<<dim3(8, 64), 256, 0, stream>>>(rhb, Wub, h, xwb, out);
}

// Round 5
// 335.989 us; speedup vs baseline: 1.1538x; 1.0182x over previous
//
#include <hip/hip_runtime.h>

typedef unsigned short u16;
typedef __attribute__((ext_vector_type(8))) short bf16x8;
typedef __attribute__((ext_vector_type(4))) float f32x4;

// ---------- helpers ----------
__device__ __forceinline__ u16 f2b(float f) {
  unsigned u = __float_as_uint(f);
  u += 0x7FFFu + ((u >> 16) & 1u);   // RNE to bf16
  return (u16)(u >> 16);
}
__device__ __forceinline__ float sigm(float x) { return 1.0f / (1.0f + __expf(-x)); }
__device__ __forceinline__ float tanh_f(float x) { return 1.0f - 2.0f / (__expf(2.0f * x) + 1.0f); }

__device__ __forceinline__ void cp16(const u16* g, u16* l) {
  __builtin_amdgcn_global_load_lds(
      (const __attribute__((address_space(1))) unsigned int*)g,
      (__attribute__((address_space(3))) unsigned int*)l, 16, 0, 0);
}

// swizzle involution on bytes within an 8KB round (64 rows x 128B)
__device__ __forceinline__ int swz(int b) {
  return b ^ (((b >> 7) & 3) << 5) ^ (((b >> 9) & 1) << 4);
}

// ---------- pack kernels ----------
__global__ __launch_bounds__(256) void pack_xh(const float* __restrict__ x,
                                               const float* __restrict__ h,
                                               u16* __restrict__ xhb) {
  int idx = blockIdx.x * 256 + threadIdx.x;
  int row = idx >> 9;
  int k = (idx & 511) << 2;
  const float* src = (k < 1024) ? (x + row * 1024 + k) : (h + row * 1024 + (k - 1024));
  float4 v = *reinterpret_cast<const float4*>(src);
  ushort4 o = make_ushort4(f2b(v.x), f2b(v.y), f2b(v.z), f2b(v.w));
  *reinterpret_cast<ushort4*>(xhb + ((size_t)idx << 2)) = o;
}

__global__ __launch_bounds__(256) void pack_w1(const float* __restrict__ Wwz,
                                               const float* __restrict__ Wuz,
                                               const float* __restrict__ Wwr,
                                               const float* __restrict__ Wur,
                                               const float* __restrict__ Ww,
                                               u16* __restrict__ W1b) {
  int idx = blockIdx.x * 256 + threadIdx.x;
  int n = idx >> 9;
  int k = (idx & 511) << 2;
  float4 v = make_float4(0.f, 0.f, 0.f, 0.f);
  if (n < 1024) {
    v = (k < 1024) ? *reinterpret_cast<const float4*>(Wwz + n * 1024 + k)
                   : *reinterpret_cast<const float4*>(Wuz + n * 1024 + (k - 1024));
  } else if (n < 2048) {
    int nn = n - 1024;
    v = (k < 1024) ? *reinterpret_cast<const float4*>(Wwr + nn * 1024 + k)
                   : *reinterpret_cast<const float4*>(Wur + nn * 1024 + (k - 1024));
  } else {
    int nn = n - 2048;
    if (k < 1024) v = *reinterpret_cast<const float4*>(Ww + nn * 1024 + k);
  }
  ushort4 o = make_ushort4(f2b(v.x), f2b(v.y), f2b(v.z), f2b(v.w));
  *reinterpret_cast<ushort4*>(W1b + ((size_t)idx << 2)) = o;
}

__global__ __launch_bounds__(256) void pack_wu(const float* __restrict__ Wu,
                                               u16* __restrict__ Wub) {
  int idx = blockIdx.x * 256 + threadIdx.x;
  float4 v = *reinterpret_cast<const float4*>(Wu + ((size_t)idx << 2));
  ushort4 o = make_ushort4(f2b(v.x), f2b(v.y), f2b(v.z), f2b(v.w));
  *reinterpret_cast<ushort4*>(Wub + ((size_t)idx << 2)) = o;
}

// ---------- 256x128 4-phase-per-K-tile core ----------
// C[256x128] = A[256xK] @ B[128xK]^T, both row-major bf16, pre-offset to tile origin.
// 8 waves = 4M x 2N, wave tile 64x64, acc[4][4]. BK=64.
// A buffer 32KB = 4 rounds of (64 rows x 128B), B buffer 16KB = 2 rounds; swizzled.
__device__ __forceinline__ void body(int t, int NT,
                                     const u16* __restrict__ Ag, const u16* __restrict__ Bg,
                                     int lda, int ldb,
                                     const u16* Ar, const u16* Br, u16* Aw, u16* Bw,
                                     int r0, int c2, int arl0, int arl1,
                                     int wr, int wc, int tid, f32x4 acc[4][4]) {
  const int ab = wr * 4096;   // wave's A round (u16 units)
  const int bb = wc * 4096;   // wave's B round
  // ---- phase q0 ----
  bf16x8 af0[2][2], bfr[4][2];
#pragma unroll
  for (int mm = 0; mm < 2; ++mm) {
    af0[mm][0] = *reinterpret_cast<const bf16x8*>(Ar + ab + mm * 1024 + arl0);
    af0[mm][1] = *reinterpret_cast<const bf16x8*>(Ar + ab + mm * 1024 + arl1);
  }
#pragma unroll
  for (int nf = 0; nf < 4; ++nf) {
    bfr[nf][0] = *reinterpret_cast<const bf16x8*>(Br + bb + nf * 1024 + arl0);
    bfr[nf][1] = *reinterpret_cast<const bf16x8*>(Br + bb + nf * 1024 + arl1);
  }
  if (t + 1 < NT) {
    // stage A(t+1), both halves, into the other A buffer
    const u16* g0 = Ag + (size_t)r0 * lda + c2 + (size_t)(t + 1) * 64;
    u16* l0 = Aw + tid * 8;
    cp16(g0, l0); cp16(g0 + (size_t)64 * lda, l0 + 4096);
    const u16* g1 = Ag + (size_t)(128 + r0) * lda + c2 + (size_t)(t + 1) * 64;
    u16* l1 = Aw + 8192 + tid * 8;
    cp16(g1, l1); cp16(g1 + (size_t)64 * lda, l1 + 4096);
  }
  __builtin_amdgcn_s_barrier();
  __builtin_amdgcn_s_setprio(1);
#pragma unroll
  for (int mm = 0; mm < 2; ++mm)
#pragma unroll
    for (int nf = 0; nf < 4; ++nf)
#pragma unroll
      for (int ks = 0; ks < 2; ++ks)
        acc[mm][nf] = __builtin_amdgcn_mfma_f32_16x16x32_bf16(
            af0[mm][ks], bfr[nf][ks], acc[mm][nf], 0, 0, 0);
  __builtin_amdgcn_s_setprio(0);
  __builtin_amdgcn_s_barrier();
  // ---- phase q1 ----
  bf16x8 af1[2][2];
#pragma unroll
  for (int mm = 0; mm < 2; ++mm) {
    af1[mm][0] = *reinterpret_cast<const bf16x8*>(Ar + ab + (2 + mm) * 1024 + arl0);
    af1[mm][1] = *reinterpret_cast<const bf16x8*>(Ar + ab + (2 + mm) * 1024 + arl1);
  }
  if (t + 2 < NT) {
    // stage B(t+2) into the CURRENT B buffer (fully consumed at q0)
    const u16* g = Bg + (size_t)r0 * ldb + c2 + (size_t)(t + 2) * 64;
    u16* l = Bw + tid * 8;
    cp16(g, l); cp16(g + (size_t)64 * ldb, l + 4096);
    asm volatile("s_waitcnt vmcnt(2)" ::: "memory");   // drain B(t+1)+A(t+1); keep B(t+2) flying
  } else {
    asm volatile("s_waitcnt vmcnt(0)" ::: "memory");   // tail: drain all
  }
  __builtin_amdgcn_s_barrier();
  __builtin_amdgcn_s_setprio(1);
#pragma unroll
  for (int mm = 0; mm < 2; ++mm)
#pragma unroll
    for (int nf = 0; nf < 4; ++nf)
#pragma unroll
      for (int ks = 0; ks < 2; ++ks)
        acc[2 + mm][nf] = __builtin_amdgcn_mfma_f32_16x16x32_bf16(
            af1[mm][ks], bfr[nf][ks], acc[2 + mm][nf], 0, 0, 0);
  __builtin_amdgcn_s_setprio(0);
  __builtin_amdgcn_s_barrier();
}

__device__ __forceinline__ void core(const u16* __restrict__ Ag, const u16* __restrict__ Bg,
                                     int lda, int ldb, int NT,
                                     u16* As0, u16* As1, u16* Bs0, u16* Bs1,
                                     f32x4 acc[4][4]) {
  const int tid = threadIdx.x;
  const int lane = tid & 63;
  const int wid = tid >> 6;
  const int wr = wid >> 1;   // 0..3 (M)
  const int wc = wid & 1;    // 0..1 (N)

  // staging decode: physical byte p = tid*16 within 8KB round; logical = swz(p)
  const int plo = tid * 16;
  const int olo = swz(plo);
  const int r0 = olo >> 7;          // row within round (0..63)
  const int c2 = (olo & 127) >> 1;  // u16 col

  // swizzled fragment-read offsets (u16 units)
  const int frow = lane & 15;
  const int fcb = (lane >> 4) * 16;
  const int mask = ((frow & 3) << 5) | (((frow >> 2) & 1) << 4);
  const int arl0 = (frow * 128 + ((fcb + 0) ^ mask)) >> 1;
  const int arl1 = (frow * 128 + ((fcb + 64) ^ mask)) >> 1;

  // prologue: A(0)->As0, B(0)->Bs0, B(1)->Bs1
  {
    const u16* g; u16* l;
    g = Ag + (size_t)r0 * lda + c2;          l = As0 + tid * 8;        cp16(g, l); cp16(g + (size_t)64 * lda, l + 4096);
    g = Ag + (size_t)(128 + r0) * lda + c2;  l = As0 + 8192 + tid * 8; cp16(g, l); cp16(g + (size_t)64 * lda, l + 4096);
    g = Bg + (size_t)r0 * ldb + c2;          l = Bs0 + tid * 8;        cp16(g, l); cp16(g + (size_t)64 * ldb, l + 4096);
    g = Bg + (size_t)r0 * ldb + c2 + 64;     l = Bs1 + tid * 8;        cp16(g, l); cp16(g + (size_t)64 * ldb, l + 4096);
  }
  asm volatile("s_waitcnt vmcnt(2)" ::: "memory");   // A(0),B(0) landed; B(1) in flight
  __builtin_amdgcn_s_barrier();

  for (int u = 0; u < NT; u += 2) {
    body(u,     NT, Ag, Bg, lda, ldb, As0, Bs0, As1, Bs0, r0, c2, arl0, arl1, wr, wc, tid, acc);
    body(u + 1, NT, Ag, Bg, lda, ldb, As1, Bs1, As0, Bs1, r0, c2, arl0, arl1, wr, wc, tid, acc);
  }
}

#define CORE_PRE()                                           \
  __shared__ u16 As0[16384];                                 \
  __shared__ u16 As1[16384];                                 \
  __shared__ u16 Bs0[8192];                                  \
  __shared__ u16 Bs1[8192];                                  \
  f32x4 acc[4][4];                                           \
  _Pragma("unroll") for (int m = 0; m < 4; ++m)              \
  _Pragma("unroll") for (int n = 0; n < 4; ++n)              \
      acc[m][n] = (f32x4){0.f, 0.f, 0.f, 0.f};

// GEMM z/r: [8192 x 2048] = xhb[8192x2048] @ W1b(rows 0..2047)^T. grid 512
__global__ __launch_bounds__(512, 2) void gemm_zr(const u16* __restrict__ xhb,
                                                  const u16* __restrict__ W1b,
                                                  const float* __restrict__ h,
                                                  float* __restrict__ zout,
                                                  u16* __restrict__ rhb) {
  int b = blockIdx.x;
  int wg = (b & 7) * 64 + (b >> 3);   // XCD chunking (512 % 8 == 0, bijective)
  int nb = wg >> 5, mb = wg & 31;     // nb 0..15, mb 0..31
  const int m0 = mb * 256, n0 = nb * 128;
  CORE_PRE();
  core(xhb + (size_t)m0 * 2048, W1b + (size_t)n0 * 2048, 2048, 2048, 32,
       As0, As1, Bs0, Bs1, acc);

  const int lane = threadIdx.x & 63;
  const int wid = threadIdx.x >> 6;
  const int wr = wid >> 1, wc = wid & 1;
  const int rbase = m0 + wr * 64 + ((lane >> 4) << 2);
  const int cbase = n0 + wc * 64 + (lane & 15);
  const int isz = (n0 < 1024);   // block-uniform region
#pragma unroll
  for (int m = 0; m < 4; ++m) {
#pragma unroll
    for (int nf = 0; nf < 4; ++nf) {
      const int col = cbase + nf * 16;
#pragma unroll
      for (int j = 0; j < 4; ++j) {
        const int row = rbase + m * 16 + j;
        const float v = acc[m][nf][j];
        if (isz) {
          zout[(size_t)row * 1024 + col] = sigm(v);
        } else {
          const size_t idx = (size_t)row * 1024 + (col - 1024);
          rhb[idx] = f2b(sigm(v) * h[idx]);
        }
      }
    }
  }
}

// GEMM w: [8192 x 1024] = x(=xhb cols 0..1023) @ Ww^T -> xwb fp32. grid 256
__global__ __launch_bounds__(512, 2) void gemm_w(const u16* __restrict__ xhb,
                                                 const u16* __restrict__ W1b,
                                                 float* __restrict__ xwb) {
  int b = blockIdx.x;
  int wg = (b & 7) * 32 + (b >> 3);
  int nb = wg >> 5, mb = wg & 31;     // nb 0..7, mb 0..31
  const int m0 = mb * 256, n0 = nb * 128;
  CORE_PRE();
  core(xhb + (size_t)m0 * 2048, W1b + (size_t)(2048 + n0) * 2048, 2048, 2048, 16,
       As0, As1, Bs0, Bs1, acc);

  const int lane = threadIdx.x & 63;
  const int wid = threadIdx.x >> 6;
  const int wr = wid >> 1, wc = wid & 1;
  const int rbase = m0 + wr * 64 + ((lane >> 4) << 2);
  const int cbase = n0 + wc * 64 + (lane & 15);
#pragma unroll
  for (int m = 0; m < 4; ++m)
#pragma unroll
    for (int nf = 0; nf < 4; ++nf)
#pragma unroll
      for (int j = 0; j < 4; ++j)
        xwb[(size_t)(rbase + m * 16 + j) * 1024 + cbase + nf * 16] = acc[m][nf][j];
}

// GEMM2: C2 = rhb @ Wub^T; out = z*h + (1-z)*tanh(C2 + xw). grid 256
__global__ __launch_bounds__(512, 2) void gemm2_k(const u16* __restrict__ rhb,
                                                  const u16* __restrict__ Wub,
                                                  const float* __restrict__ h,
                                                  const float* __restrict__ xwb,
                                                  float* __restrict__ out) {  // holds z
  int b = blockIdx.x;
  int wg = (b & 7) * 32 + (b >> 3);
  int nb = wg >> 5, mb = wg & 31;
  const int m0 = mb * 256, n0 = nb * 128;
  CORE_PRE();
  core(rhb + (size_t)m0 * 1024, Wub + (size_t)n0 * 1024, 1024, 1024, 16,
       As0, As1, Bs0, Bs1, acc);

  const int lane = threadIdx.x & 63;
  const int wid = threadIdx.x >> 6;
  const int wr = wid >> 1, wc = wid & 1;
  const int rbase = m0 + wr * 64 + ((lane >> 4) << 2);
  const int cbase = n0 + wc * 64 + (lane & 15);
#pragma unroll
  for (int m = 0; m < 4; ++m) {
#pragma unroll
    for (int nf = 0; nf < 4; ++nf) {
      const int col = cbase + nf * 16;
#pragma unroll
      for (int j = 0; j < 4; ++j) {
        const int row = rbase + m * 16 + j;
        const size_t idx = (size_t)row * 1024 + col;
        const float z = out[idx];
        const float hv = h[idx];
        const float ht = tanh_f(acc[m][nf][j] + xwb[idx]);
        out[idx] = z * hv + (1.0f - z) * ht;
      }
    }
  }
}

// ---------- launch ----------
extern "C" void kernel_launch(void* const* d_in, const int* in_sizes, int n_in,
                              void* d_out, int out_size, void* d_ws, size_t ws_size,
                              hipStream_t stream) {
  const float* x   = (const float*)d_in[0];
  const float* h   = (const float*)d_in[1];
  const float* Wwz = (const float*)d_in[2];
  const float* Wuz = (const float*)d_in[3];
  const float* Wwr = (const float*)d_in[4];
  const float* Wur = (const float*)d_in[5];
  const float* Wu  = (const float*)d_in[6];
  const float* Ww  = (const float*)d_in[7];
  float* out = (float*)d_out;

  char* ws = (char*)d_ws;
  u16*   xhb = (u16*)(ws);                      // 33,554,432
  u16*   W1b = (u16*)(ws + 33554432);           // 12,582,912
  u16*   Wub = (u16*)(ws + 46137344);           //  2,097,152
  u16*   rhb = (u16*)(ws + 48234496);           // 16,777,216
  float* xwb = (float*)(ws + 65011712);         // 33,554,432

  pack_xh<<<16384, 256, 0, stream>>>(x, h, xhb);
  pack_w1<<<6144, 256, 0, stream>>>(Wwz, Wuz, Wwr, Wur, Ww, W1b);
  pack_wu<<<1024, 256, 0, stream>>>(Wu, Wub);
  gemm_zr<<<512, 512, 0, stream>>>(xhb, W1b, h, out, rhb);
  gemm_w<<<256, 512, 0, stream>>>(xhb, W1b, xwb);
  gemm2_k<<<256, 512, 0, stream>>>(rhb, Wub, h, xwb, out);
}

// Round 6
// 308.127 us; speedup vs baseline: 1.2581x; 1.0904x over previous
//
#include <hip/hip_runtime.h>

typedef unsigned short u16;
typedef __attribute__((ext_vector_type(8))) short bf16x8;
typedef __attribute__((ext_vector_type(4))) float f32x4;

// ---------- helpers ----------
__device__ __forceinline__ u16 f2b(float f) {
  unsigned u = __float_as_uint(f);
  u += 0x7FFFu + ((u >> 16) & 1u);   // RNE to bf16
  return (u16)(u >> 16);
}
__device__ __forceinline__ float b2f(u16 v) { return __uint_as_float(((unsigned)v) << 16); }
__device__ __forceinline__ float sigm(float x) { return 1.0f / (1.0f + __expf(-x)); }
__device__ __forceinline__ float tanh_f(float x) { return 1.0f - 2.0f / (__expf(2.0f * x) + 1.0f); }

__device__ __forceinline__ void cp16(const u16* g, u16* l) {
  __builtin_amdgcn_global_load_lds(
      (const __attribute__((address_space(1))) unsigned int*)g,
      (__attribute__((address_space(3))) unsigned int*)l, 16, 0, 0);
}

// swizzle involution on bytes within an 8KB round (64 rows x 128B)
__device__ __forceinline__ int swz(int b) {
  return b ^ (((b >> 7) & 3) << 5) ^ (((b >> 9) & 1) << 4);
}

// ---------- pack kernels ----------
__global__ __launch_bounds__(256) void pack_xh(const float* __restrict__ x,
                                               const float* __restrict__ h,
                                               u16* __restrict__ xhb) {
  int idx = blockIdx.x * 256 + threadIdx.x;
  int row = idx >> 9;
  int k = (idx & 511) << 2;
  const float* src = (k < 1024) ? (x + row * 1024 + k) : (h + row * 1024 + (k - 1024));
  float4 v = *reinterpret_cast<const float4*>(src);
  ushort4 o = make_ushort4(f2b(v.x), f2b(v.y), f2b(v.z), f2b(v.w));
  *reinterpret_cast<ushort4*>(xhb + ((size_t)idx << 2)) = o;
}

__global__ __launch_bounds__(256) void pack_w1(const float* __restrict__ Wwz,
                                               const float* __restrict__ Wuz,
                                               const float* __restrict__ Wwr,
                                               const float* __restrict__ Wur,
                                               const float* __restrict__ Ww,
                                               u16* __restrict__ W1b) {
  int idx = blockIdx.x * 256 + threadIdx.x;
  int n = idx >> 9;
  int k = (idx & 511) << 2;
  float4 v = make_float4(0.f, 0.f, 0.f, 0.f);
  if (n < 1024) {
    v = (k < 1024) ? *reinterpret_cast<const float4*>(Wwz + n * 1024 + k)
                   : *reinterpret_cast<const float4*>(Wuz + n * 1024 + (k - 1024));
  } else if (n < 2048) {
    int nn = n - 1024;
    v = (k < 1024) ? *reinterpret_cast<const float4*>(Wwr + nn * 1024 + k)
                   : *reinterpret_cast<const float4*>(Wur + nn * 1024 + (k - 1024));
  } else {
    int nn = n - 2048;
    if (k < 1024) v = *reinterpret_cast<const float4*>(Ww + nn * 1024 + k);
  }
  ushort4 o = make_ushort4(f2b(v.x), f2b(v.y), f2b(v.z), f2b(v.w));
  *reinterpret_cast<ushort4*>(W1b + ((size_t)idx << 2)) = o;
}

__global__ __launch_bounds__(256) void pack_wu(const float* __restrict__ Wu,
                                               u16* __restrict__ Wub) {
  int idx = blockIdx.x * 256 + threadIdx.x;
  float4 v = *reinterpret_cast<const float4*>(Wu + ((size_t)idx << 2));
  ushort4 o = make_ushort4(f2b(v.x), f2b(v.y), f2b(v.z), f2b(v.w));
  *reinterpret_cast<ushort4*>(Wub + ((size_t)idx << 2)) = o;
}

// ---------- 256x128 core, depth-2 prefetch (triple-buffered) ----------
// C[256x128] = A[256xK] @ B[128xK]^T, row-major bf16, pre-offset to tile origin.
// 8 waves = 4M x 2N, wave tile 64x64. BK=64. Tile t stages tile t+2.
__device__ __forceinline__ void body(int t, int NT,
                                     const u16* __restrict__ Ag, const u16* __restrict__ Bg,
                                     int lda, int ldb,
                                     const u16* Ar, const u16* Br, u16* Aw, u16* Bw,
                                     int r0, int c2, int arl0, int arl1,
                                     int wr, int wc, int tid, f32x4 acc[4][4]) {
  const int ab = wr * 4096;   // wave's A round (u16 units)
  const int bb = wc * 4096;   // wave's B round
  const bool pf = (t + 2 < NT);
  // ---- phase q0: read A-low + all B frags; stage A(t+2) ----
  bf16x8 af0[2][2], bfr[4][2];
#pragma unroll
  for (int mm = 0; mm < 2; ++mm) {
    af0[mm][0] = *reinterpret_cast<const bf16x8*>(Ar + ab + mm * 1024 + arl0);
    af0[mm][1] = *reinterpret_cast<const bf16x8*>(Ar + ab + mm * 1024 + arl1);
  }
#pragma unroll
  for (int nf = 0; nf < 4; ++nf) {
    bfr[nf][0] = *reinterpret_cast<const bf16x8*>(Br + bb + nf * 1024 + arl0);
    bfr[nf][1] = *reinterpret_cast<const bf16x8*>(Br + bb + nf * 1024 + arl1);
  }
  if (pf) {
    const u16* g0 = Ag + (size_t)r0 * lda + c2 + (size_t)(t + 2) * 64;
    u16* l0 = Aw + tid * 8;
    cp16(g0, l0); cp16(g0 + (size_t)64 * lda, l0 + 4096);
    const u16* g1 = Ag + (size_t)(128 + r0) * lda + c2 + (size_t)(t + 2) * 64;
    u16* l1 = Aw + 8192 + tid * 8;
    cp16(g1, l1); cp16(g1 + (size_t)64 * lda, l1 + 4096);
  }
  __builtin_amdgcn_s_barrier();
  __builtin_amdgcn_s_setprio(1);
#pragma unroll
  for (int mm = 0; mm < 2; ++mm)
#pragma unroll
    for (int nf = 0; nf < 4; ++nf)
#pragma unroll
      for (int ks = 0; ks < 2; ++ks)
        acc[mm][nf] = __builtin_amdgcn_mfma_f32_16x16x32_bf16(
            af0[mm][ks], bfr[nf][ks], acc[mm][nf], 0, 0, 0);
  __builtin_amdgcn_s_setprio(0);
  __builtin_amdgcn_s_barrier();
  // ---- phase q1: read A-high frags; stage B(t+2) ----
  bf16x8 af1[2][2];
#pragma unroll
  for (int mm = 0; mm < 2; ++mm) {
    af1[mm][0] = *reinterpret_cast<const bf16x8*>(Ar + ab + (2 + mm) * 1024 + arl0);
    af1[mm][1] = *reinterpret_cast<const bf16x8*>(Ar + ab + (2 + mm) * 1024 + arl1);
  }
  if (pf) {
    const u16* g = Bg + (size_t)r0 * ldb + c2 + (size_t)(t + 2) * 64;
    u16* l = Bw + tid * 8;
    cp16(g, l); cp16(g + (size_t)64 * ldb, l + 4096);
  }
  __builtin_amdgcn_s_barrier();
  __builtin_amdgcn_s_setprio(1);
#pragma unroll
  for (int mm = 0; mm < 2; ++mm)
#pragma unroll
    for (int nf = 0; nf < 4; ++nf)
#pragma unroll
      for (int ks = 0; ks < 2; ++ks)
        acc[2 + mm][nf] = __builtin_amdgcn_mfma_f32_16x16x32_bf16(
            af1[mm][ks], bfr[nf][ks], acc[2 + mm][nf], 0, 0, 0);
  __builtin_amdgcn_s_setprio(0);
  // steady state: 12 outstanding (t+1's 6 + t+2's 6); keep t+2's 6 in flight
  if (pf) asm volatile("s_waitcnt vmcnt(6)" ::: "memory");
  else    asm volatile("s_waitcnt vmcnt(0)" ::: "memory");
  __builtin_amdgcn_s_barrier();
}

__device__ __forceinline__ void core(const u16* __restrict__ Ag, const u16* __restrict__ Bg,
                                     int lda, int ldb, int NT,
                                     u16* As0, u16* As1, u16* As2,
                                     u16* Bs0, u16* Bs1, u16* Bs2,
                                     f32x4 acc[4][4]) {
  const int tid = threadIdx.x;
  const int lane = tid & 63;
  const int wid = tid >> 6;
  const int wr = wid >> 1;   // 0..3 (M)
  const int wc = wid & 1;    // 0..1 (N)

  // staging decode: physical byte p = tid*16 within 8KB round; logical = swz(p)
  const int plo = tid * 16;
  const int olo = swz(plo);
  const int r0 = olo >> 7;          // row within round (0..63)
  const int c2 = (olo & 127) >> 1;  // u16 col

  // swizzled fragment-read offsets (u16 units)
  const int frow = lane & 15;
  const int fcb = (lane >> 4) * 16;
  const int mask = ((frow & 3) << 5) | (((frow >> 2) & 1) << 4);
  const int arl0 = (frow * 128 + ((fcb + 0) ^ mask)) >> 1;
  const int arl1 = (frow * 128 + ((fcb + 64) ^ mask)) >> 1;

  auto stA = [&](u16* buf, int tg) {
    const u16* g0 = Ag + (size_t)r0 * lda + c2 + (size_t)tg * 64;
    u16* l0 = buf + tid * 8;
    cp16(g0, l0); cp16(g0 + (size_t)64 * lda, l0 + 4096);
    const u16* g1 = Ag + (size_t)(128 + r0) * lda + c2 + (size_t)tg * 64;
    u16* l1 = buf + 8192 + tid * 8;
    cp16(g1, l1); cp16(g1 + (size_t)64 * lda, l1 + 4096);
  };
  auto stB = [&](u16* buf, int tg) {
    const u16* g = Bg + (size_t)r0 * ldb + c2 + (size_t)tg * 64;
    u16* l = buf + tid * 8;
    cp16(g, l); cp16(g + (size_t)64 * ldb, l + 4096);
  };

  // prologue: tiles 0 and 1 (issue order matters for vmcnt ledger)
  stA(As0, 0); stB(Bs0, 0);          // 6 oldest
  stA(As1, 1); stB(Bs1, 1);          // 6 newest
  asm volatile("s_waitcnt vmcnt(6)" ::: "memory");   // tile0 landed; tile1 in flight
  __builtin_amdgcn_s_barrier();

  for (int u = 0; u < NT; u += 3) {
    body(u, NT, Ag, Bg, lda, ldb, As0, Bs0, As2, Bs2, r0, c2, arl0, arl1, wr, wc, tid, acc);
    if (u + 1 < NT)
      body(u + 1, NT, Ag, Bg, lda, ldb, As1, Bs1, As0, Bs0, r0, c2, arl0, arl1, wr, wc, tid, acc);
    if (u + 2 < NT)
      body(u + 2, NT, Ag, Bg, lda, ldb, As2, Bs2, As1, Bs1, r0, c2, arl0, arl1, wr, wc, tid, acc);
  }
}

#define CORE_PRE()                                           \
  __shared__ u16 As0[16384];                                 \
  __shared__ u16 As1[16384];                                 \
  __shared__ u16 As2[16384];                                 \
  __shared__ u16 Bs0[8192];                                  \
  __shared__ u16 Bs1[8192];                                  \
  __shared__ u16 Bs2[8192];                                  \
  f32x4 acc[4][4];                                           \
  _Pragma("unroll") for (int m = 0; m < 4; ++m)              \
  _Pragma("unroll") for (int n = 0; n < 4; ++n)              \
      acc[m][n] = (f32x4){0.f, 0.f, 0.f, 0.f};

// GEMM z/r: [8192 x 2048] = xhb @ W1b(rows 0..2047)^T. grid 512, m-major XCD chunks
__global__ __launch_bounds__(512, 2) void gemm_zr(const u16* __restrict__ xhb,
                                                  const u16* __restrict__ W1b,
                                                  const float* __restrict__ h,
                                                  float* __restrict__ zout,
                                                  u16* __restrict__ rhb) {
  int b = blockIdx.x;
  int wg = (b & 7) * 64 + (b >> 3);   // XCD gets contiguous 64-wg chunk
  int mb = wg >> 4, nb = wg & 15;     // m-major within chunk: 4 m-panels x all 16 nb
  const int m0 = mb * 256, n0 = nb * 128;
  CORE_PRE();
  core(xhb + (size_t)m0 * 2048, W1b + (size_t)n0 * 2048, 2048, 2048, 32,
       As0, As1, As2, Bs0, Bs1, Bs2, acc);

  const int lane = threadIdx.x & 63;
  const int wid = threadIdx.x >> 6;
  const int wr = wid >> 1, wc = wid & 1;
  const int rbase = m0 + wr * 64 + ((lane >> 4) << 2);
  const int cbase = n0 + wc * 64 + (lane & 15);
  const int isz = (n0 < 1024);
#pragma unroll
  for (int m = 0; m < 4; ++m) {
#pragma unroll
    for (int nf = 0; nf < 4; ++nf) {
      const int col = cbase + nf * 16;
#pragma unroll
      for (int j = 0; j < 4; ++j) {
        const int row = rbase + m * 16 + j;
        const float v = acc[m][nf][j];
        if (isz) {
          zout[(size_t)row * 1024 + col] = sigm(v);
        } else {
          const size_t idx = (size_t)row * 1024 + (col - 1024);
          rhb[idx] = f2b(sigm(v) * h[idx]);
        }
      }
    }
  }
}

// GEMM w: [8192 x 1024] = x @ Ww^T -> xwb bf16. grid 256
__global__ __launch_bounds__(512, 2) void gemm_w(const u16* __restrict__ xhb,
                                                 const u16* __restrict__ W1b,
                                                 u16* __restrict__ xwb) {
  int b = blockIdx.x;
  int wg = (b & 7) * 32 + (b >> 3);
  int mb = wg >> 3, nb = wg & 7;
  const int m0 = mb * 256, n0 = nb * 128;
  CORE_PRE();
  core(xhb + (size_t)m0 * 2048, W1b + (size_t)(2048 + n0) * 2048, 2048, 2048, 16,
       As0, As1, As2, Bs0, Bs1, Bs2, acc);

  const int lane = threadIdx.x & 63;
  const int wid = threadIdx.x >> 6;
  const int wr = wid >> 1, wc = wid & 1;
  const int rbase = m0 + wr * 64 + ((lane >> 4) << 2);
  const int cbase = n0 + wc * 64 + (lane & 15);
#pragma unroll
  for (int m = 0; m < 4; ++m)
#pragma unroll
    for (int nf = 0; nf < 4; ++nf)
#pragma unroll
      for (int j = 0; j < 4; ++j)
        xwb[(size_t)(rbase + m * 16 + j) * 1024 + cbase + nf * 16] = f2b(acc[m][nf][j]);
}

// GEMM2: C2 = rhb @ Wub^T; out = z*h + (1-z)*tanh(C2 + xw). grid 256
__global__ __launch_bounds__(512, 2) void gemm2_k(const u16* __restrict__ rhb,
                                                  const u16* __restrict__ Wub,
                                                  const float* __restrict__ h,
                                                  const u16* __restrict__ xwb,
                                                  float* __restrict__ out) {  // holds z
  int b = blockIdx.x;
  int wg = (b & 7) * 32 + (b >> 3);
  int mb = wg >> 3, nb = wg & 7;
  const int m0 = mb * 256, n0 = nb * 128;
  CORE_PRE();
  core(rhb + (size_t)m0 * 1024, Wub + (size_t)n0 * 1024, 1024, 1024, 16,
       As0, As1, As2, Bs0, Bs1, Bs2, acc);

  const int lane = threadIdx.x & 63;
  const int wid = threadIdx.x >> 6;
  const int wr = wid >> 1, wc = wid & 1;
  const int rbase = m0 + wr * 64 + ((lane >> 4) << 2);
  const int cbase = n0 + wc * 64 + (lane & 15);
#pragma unroll
  for (int m = 0; m < 4; ++m) {
#pragma unroll
    for (int nf = 0; nf < 4; ++nf) {
      const int col = cbase + nf * 16;
#pragma unroll
      for (int j = 0; j < 4; ++j) {
        const int row = rbase + m * 16 + j;
        const size_t idx = (size_t)row * 1024 + col;
        const float z = out[idx];
        const float hv = h[idx];
        const float ht = tanh_f(acc[m][nf][j] + b2f(xwb[idx]));
        out[idx] = z * hv + (1.0f - z) * ht;
      }
    }
  }
}

// ---------- launch ----------
extern "C" void kernel_launch(void* const* d_in, const int* in_sizes, int n_in,
                              void* d_out, int out_size, void* d_ws, size_t ws_size,
                              hipStream_t stream) {
  const float* x   = (const float*)d_in[0];
  const float* h   = (const float*)d_in[1];
  const float* Wwz = (const float*)d_in[2];
  const float* Wuz = (const float*)d_in[3];
  const float* Wwr = (const float*)d_in[4];
  const float* Wur = (const float*)d_in[5];
  const float* Wu  = (const float*)d_in[6];
  const float* Ww  = (const float*)d_in[7];
  float* out = (float*)d_out;

  char* ws = (char*)d_ws;
  u16*   xhb = (u16*)(ws);                      // 33,554,432
  u16*   W1b = (u16*)(ws + 33554432);           // 12,582,912
  u16*   Wub = (u16*)(ws + 46137344);           //  2,097,152
  u16*   rhb = (u16*)(ws + 48234496);           // 16,777,216
  u16*   xwb = (u16*)(ws + 65011712);           // 16,777,216 (bf16 now)

  pack_xh<<<16384, 256, 0, stream>>>(x, h, xhb);
  pack_w1<<<6144, 256, 0, stream>>>(Wwz, Wuz, Wwr, Wur, Ww, W1b);
  pack_wu<<<1024, 256, 0, stream>>>(Wu, Wub);
  gemm_zr<<<512, 512, 0, stream>>>(xhb, W1b, h, out, rhb);
  gemm_w<<<256, 512, 0, stream>>>(xhb, W1b, xwb);
  gemm2_k<<<256, 512, 0, stream>>>(rhb, Wub, h, xwb, out);
}